// Round 5
// baseline (251.353 us; speedup 1.0000x reference)
//
#include <hip/hip_runtime.h>

// N=4096, A=512, C=100 (derived at launch).
// Outputs flat: [loss(1), new_cov(C*A*A), new_ave(C*A), new_amount(C)]
//
// 2 dispatches:
//   prep : 1 block — histogram, scan, per-class scalars, counting-sort, zero loss.
//   mega : grid (A/TM, A/TM, LZ+AZ+CZ) sized to ~3 blocks/CU (768 blocks total):
//            z in [0,LZ)      : CE-loss rider blocks.
//            z in [LZ,LZ+AZ)  : new_ave rider blocks (one class per block).
//            z >= LZ+AZ       : PERSISTENT cov blocks — fixed 128x128 tile
//                               position, looping classes c = zc, zc+CZ, ...
//                               Class c's store burst overlaps class c+1's
//                               prologue/K-loop inside the block (spreads HBM
//                               writes; kills scheduling-round quantization:
//                               round-4 ran 1600 blocks in 2.1 rounds of 768).
//          Cov tile: RAW outer products (E[xx^T]-mu mu^T identity), REGISTER-staged
//          float4 gather (keeps feats L2-resident: round-2 DMA staging amplified
//          HBM traffic 4x), LDS double-buffer -> ONE barrier per k-chunk,
//          per-thread scalar column sums, idx prefetched to LDS,
//          nontemporal streaming stores, cov_in read skipped when w==1.
//
// NOTE: plain __launch_bounds__(256). Round-3's (256,4) capped VGPR at 64 and
// spilled the 64-float accumulator to scratch (+395 MB HBM traffic, 2x dur).
// This kernel wants ~150 VGPRs / 3 waves per EU / 3 blocks per CU.

#define TM 128
#define KC 16      // members per k-chunk
#define LSTR 132   // padded LDS row stride (floats)
#define LZ 8       // loss z-slices

typedef float nf4 __attribute__((ext_vector_type(4)));   // nontemporal vector

// ---------------- prep ----------------
__global__ __launch_bounds__(1024) void prep_kernel(
    const int* __restrict__ labels, const float* __restrict__ Amount,
    int* __restrict__ offsets, int* __restrict__ idx_sorted,
    float* __restrict__ w_arr, float* __restrict__ inv_cs,
    float* __restrict__ amount_out, float* __restrict__ out_loss0, int N, int C) {
    __shared__ int hist[1024];
    __shared__ int offs[1025];
    __shared__ int cur[1024];
    const int tid = threadIdx.x;
    for (int c = tid; c < C; c += 1024) { hist[c] = 0; cur[c] = 0; }
    __syncthreads();
    for (int i = tid; i < N; i += 1024) atomicAdd(&hist[labels[i]], 1);
    __syncthreads();
    if (tid == 0) {
        int o = 0;
        for (int c = 0; c < C; ++c) { offs[c] = o; o += hist[c]; }
        offs[C] = o;
    }
    __syncthreads();
    for (int c = tid; c < C; c += 1024) {
        float cf = (float)hist[c];
        float cs = cf > 0.f ? cf : 1.f;
        inv_cs[c] = 1.f / cs;
        float am = Amount[c];
        float dn = cf + am;
        w_arr[c] = dn > 0.f ? cf / dn : 0.f;
        amount_out[c] = am + cf;
        offsets[c] = offs[c];
    }
    if (tid == 0) { offsets[C] = offs[C]; out_loss0[0] = 0.f; }
    for (int i = tid; i < N; i += 1024) {
        int c = labels[i];
        int p = atomicAdd(&cur[c], 1);
        idx_sorted[offs[c] + p] = i;
    }
}

// ---------------- mega: loss riders + ave riders + persistent cov ----------------
__global__ __launch_bounds__(256) void cov_kernel(
    const float* __restrict__ feats, const float* __restrict__ cov_in,
    const float* __restrict__ Ave_in, const float* __restrict__ y_s,
    const int* __restrict__ labels,
    const int* __restrict__ idx_sorted, const int* __restrict__ offsets,
    const float* __restrict__ w_arr, const float* __restrict__ inv_cs,
    float* __restrict__ out_cov, float* __restrict__ out_ave,
    float* __restrict__ out_loss0,
    int N, int C, int A, float invN, int AZ) {

    const int nxy = gridDim.x * gridDim.y;
    const int bxy = blockIdx.y * gridDim.x + blockIdx.x;

    // ---- loss rider blocks (z in [0, LZ)): LZ*nxy blocks, 4 waves each ----
    if ((int)blockIdx.z < LZ) {
        __shared__ float bsum[4];
        const int lane = threadIdx.x & 63;
        const int wv = threadIdx.x >> 6;
        const int bid = (int)blockIdx.z * nxy + bxy;
        const int nwaves = LZ * nxy * 4;
        const int gw = bid * 4 + wv;
        float wsum = 0.f;
        for (int r = gw; r < N; r += nwaves) {
            const float* row = y_s + (size_t)r * C;
            float m = -1e30f;
            for (int col = lane; col < C; col += 64) m = fmaxf(m, row[col]);
            #pragma unroll
            for (int off = 32; off > 0; off >>= 1) m = fmaxf(m, __shfl_xor(m, off));
            float se = 0.f;
            for (int col = lane; col < C; col += 64) se += __expf(row[col] - m);
            #pragma unroll
            for (int off = 32; off > 0; off >>= 1) se += __shfl_xor(se, off);
            if (lane == 0) wsum += -(row[labels[r]] - m - __logf(se));
        }
        if (lane == 0) bsum[wv] = wsum;
        __syncthreads();
        if (threadIdx.x == 0)
            atomicAdd(out_loss0, (bsum[0] + bsum[1] + bsum[2] + bsum[3]) * invN);
        return;
    }

    // ---- ave rider blocks (z in [LZ, LZ+AZ)): one class per block ----
    if ((int)blockIdx.z < LZ + AZ) {
        __shared__ int idxs[256];
        const int bid = ((int)blockIdx.z - LZ) * nxy + bxy;
        if (bid >= C) return;
        const int c = bid;
        const int tid = threadIdx.x;
        const int base = offsets[c];
        const int nc = offsets[c + 1] - base;
        const float w = w_arr[c];
        const float ic = inv_cs[c];
        for (int c0 = 0; c0 < A; c0 += 512) {
            const int colA = c0 + tid;
            const int colB = c0 + 256 + tid;
            float s0 = 0.f, s1 = 0.f;
            for (int i0 = 0; i0 < nc; i0 += 256) {
                int chunk = min(256, nc - i0);
                __syncthreads();
                if (tid < chunk) idxs[tid] = idx_sorted[base + i0 + tid];
                __syncthreads();
                int j = 0;
                for (; j + 3 < chunk; j += 4) {
                    const float* f0 = feats + (size_t)idxs[j] * A;
                    const float* f1 = feats + (size_t)idxs[j + 1] * A;
                    const float* f2 = feats + (size_t)idxs[j + 2] * A;
                    const float* f3 = feats + (size_t)idxs[j + 3] * A;
                    if (colA < A) s0 += f0[colA] + f1[colA] + f2[colA] + f3[colA];
                    if (colB < A) s1 += f0[colB] + f1[colB] + f2[colB] + f3[colB];
                }
                for (; j < chunk; ++j) {
                    const float* fr = feats + (size_t)idxs[j] * A;
                    if (colA < A) s0 += fr[colA];
                    if (colB < A) s1 += fr[colB];
                }
            }
            if (colA < A)
                out_ave[(size_t)c * A + colA] =
                    Ave_in[(size_t)c * A + colA] * (1.f - w) + (s0 * ic) * w;
            if (colB < A)
                out_ave[(size_t)c * A + colB] =
                    Ave_in[(size_t)c * A + colB] * (1.f - w) + (s1 * ic) * w;
        }
        return;
    }

    // ---- persistent cov blocks: fixed tile (a0,b0), loop classes ----
    const int CZ = (int)gridDim.z - LZ - AZ;
    const int zc = (int)blockIdx.z - LZ - AZ;
    const int a0 = blockIdx.y * TM;
    const int b0 = blockIdx.x * TM;
    const int tid = threadIdx.x;

    // [buf][0=A-tile,1=B-tile][k][col], padded stride
    __shared__ float Xs[2][2][KC][LSTR];
    __shared__ float muA[TM], muB[TM], dA[TM], dB[TM];
    __shared__ int idxbuf[256];

    const int ty = tid >> 4, tx = tid & 15;
    const int ty4 = ty * 4, tx4 = tx * 4;
    const int li = ty;            // staging member row (0..15)
    const int cg = tx4;           // staging col group
    const int cside = tid >> 7;   // 0: A-tile, 1: B-tile (column-sum pass)
    const int ccol  = tid & 127;

    for (int c = zc; c < C; c += CZ) {
        const float w   = w_arr[c];
        const float omw = 1.f - w;
        const float s   = inv_cs[c] * w;
        const float aw  = w * omw;
        const size_t cbase = (size_t)c * A * A;

        if (s > 0.f) {
            const int base = offsets[c];
            const int nc = offsets[c + 1] - base;
            const int nchunks = (nc + KC - 1) / KC;

            // prefetch member indices to LDS (first loop barrier makes it visible)
            if (tid < nc && tid < 256) idxbuf[tid] = idx_sorted[base + tid];

            float4 v0, v1, v2, v3;        // pipeline registers (RAW values)
            auto LOADV = [&](int ch, bool fromLds) {
                const int slot = ch * KC + li;
                v0 = make_float4(0.f, 0.f, 0.f, 0.f); v1 = v0; v2 = v0; v3 = v0;
                if (slot < nc) {
                    int row = (fromLds && slot < 256) ? idxbuf[slot]
                                                      : idx_sorted[base + slot];
                    const float* fr = feats + (size_t)row * A;
                    v0 = *reinterpret_cast<const float4*>(fr + a0 + cg);
                    v1 = *reinterpret_cast<const float4*>(fr + a0 + cg + 64);
                    v2 = *reinterpret_cast<const float4*>(fr + b0 + cg);
                    v3 = *reinterpret_cast<const float4*>(fr + b0 + cg + 64);
                }
            };
            auto STORE_LDS = [&](int b) {
                *reinterpret_cast<float4*>(&Xs[b][0][li][cg])      = v0;
                *reinterpret_cast<float4*>(&Xs[b][0][li][cg + 64]) = v1;
                *reinterpret_cast<float4*>(&Xs[b][1][li][cg])      = v2;
                *reinterpret_cast<float4*>(&Xs[b][1][li][cg + 64]) = v3;
            };

            float acc[2][4][2][4] = {};
            if (omw != 0.f) {
                // fold cov_in*(1-w) into acc init; skipped when w==1
                const float sc = omw / s;
                #pragma unroll
                for (int ri = 0; ri < 2; ++ri)
                    #pragma unroll
                    for (int i = 0; i < 4; ++i) {
                        const size_t rowo = cbase + (size_t)(a0 + ri * 64 + ty4 + i) * A + b0;
                        #pragma unroll
                        for (int ci = 0; ci < 2; ++ci) {
                            float4 co = *reinterpret_cast<const float4*>(&cov_in[rowo + ci * 64 + tx4]);
                            acc[ri][i][ci][0] = co.x * sc;
                            acc[ri][i][ci][1] = co.y * sc;
                            acc[ri][i][ci][2] = co.z * sc;
                            acc[ri][i][ci][3] = co.w * sc;
                        }
                    }
            }

            float csum = 0.f;             // this thread's column sum

            // prologue: chunk 0 -> regs -> buf0 (idx from global; idxbuf not yet synced)
            LOADV(0, false);
            STORE_LDS(0);

            for (int ch = 0; ch < nchunks; ++ch) {
                const int cur = ch & 1;
                __syncthreads();          // buf[cur] + idxbuf visible; prev reads of buf[cur^1] done
                if (ch + 1 < nchunks) LOADV(ch + 1, true);   // loads fly under the FMA burst

                const int kn = min(KC, nc - ch * KC);
                if (kn == KC) {
                    #pragma unroll
                    for (int k = 0; k < KC; ++k) {
                        float4 a0v = *reinterpret_cast<const float4*>(&Xs[cur][0][k][ty4]);
                        float4 a1v = *reinterpret_cast<const float4*>(&Xs[cur][0][k][64 + ty4]);
                        float4 b0v = *reinterpret_cast<const float4*>(&Xs[cur][1][k][tx4]);
                        float4 b1v = *reinterpret_cast<const float4*>(&Xs[cur][1][k][64 + tx4]);
                        float af[2][4] = {{a0v.x, a0v.y, a0v.z, a0v.w}, {a1v.x, a1v.y, a1v.z, a1v.w}};
                        float bf[2][4] = {{b0v.x, b0v.y, b0v.z, b0v.w}, {b1v.x, b1v.y, b1v.z, b1v.w}};
                        #pragma unroll
                        for (int ri = 0; ri < 2; ++ri)
                            #pragma unroll
                            for (int i = 0; i < 4; ++i)
                                #pragma unroll
                                for (int ci = 0; ci < 2; ++ci)
                                    #pragma unroll
                                    for (int j = 0; j < 4; ++j)
                                        acc[ri][i][ci][j] += af[ri][i] * bf[ci][j];
                    }
                } else {
                    for (int k = 0; k < kn; ++k) {
                        float4 a0v = *reinterpret_cast<const float4*>(&Xs[cur][0][k][ty4]);
                        float4 a1v = *reinterpret_cast<const float4*>(&Xs[cur][0][k][64 + ty4]);
                        float4 b0v = *reinterpret_cast<const float4*>(&Xs[cur][1][k][tx4]);
                        float4 b1v = *reinterpret_cast<const float4*>(&Xs[cur][1][k][64 + tx4]);
                        float af[2][4] = {{a0v.x, a0v.y, a0v.z, a0v.w}, {a1v.x, a1v.y, a1v.z, a1v.w}};
                        float bf[2][4] = {{b0v.x, b0v.y, b0v.z, b0v.w}, {b1v.x, b1v.y, b1v.z, b1v.w}};
                        #pragma unroll
                        for (int ri = 0; ri < 2; ++ri)
                            #pragma unroll
                            for (int i = 0; i < 4; ++i)
                                #pragma unroll
                                for (int ci = 0; ci < 2; ++ci)
                                    #pragma unroll
                                    for (int j = 0; j < 4; ++j)
                                        acc[ri][i][ci][j] += af[ri][i] * bf[ci][j];
                    }
                }

                // column-sum pass on current buffer (zero-filled tail rows contribute 0)
                for (int k = 0; k < kn; ++k) csum += Xs[cur][cside][k][ccol];

                if (ch + 1 < nchunks) STORE_LDS(cur ^ 1);    // waits vmcnt on LOADV regs
            }

            // mu / d arrays from per-thread column sums (tid<128: A-side, else B-side)
            {
                const float ic = inv_cs[c];
                float mu = csum * ic;
                if (tid < 128) {
                    muA[ccol] = mu;
                    dA[ccol] = Ave_in[(size_t)c * A + a0 + ccol] - mu;
                } else {
                    muB[ccol] = mu;
                    dB[ccol] = Ave_in[(size_t)c * A + b0 + ccol] - mu;
                }
            }
            __syncthreads();              // also fences last Xs reads vs next class writes

            // epilogue: out = acc*s - w*muA*muB + w(1-w)*dA*dB ; nontemporal stream
            float mb[2][4], db[2][4];
            #pragma unroll
            for (int ci = 0; ci < 2; ++ci)
                #pragma unroll
                for (int j = 0; j < 4; ++j) {
                    mb[ci][j] = muB[ci * 64 + tx4 + j];
                    db[ci][j] = dB[ci * 64 + tx4 + j];
                }

            #pragma unroll
            for (int ri = 0; ri < 2; ++ri)
                #pragma unroll
                for (int i = 0; i < 4; ++i) {
                    float ma = w  * muA[ri * 64 + ty4 + i];
                    float da = aw * dA[ri * 64 + ty4 + i];
                    const size_t rowo = cbase + (size_t)(a0 + ri * 64 + ty4 + i) * A + b0;
                    #pragma unroll
                    for (int ci = 0; ci < 2; ++ci) {
                        nf4 res;
                        res.x = acc[ri][i][ci][0] * s - ma * mb[ci][0] + da * db[ci][0];
                        res.y = acc[ri][i][ci][1] * s - ma * mb[ci][1] + da * db[ci][1];
                        res.z = acc[ri][i][ci][2] * s - ma * mb[ci][2] + da * db[ci][2];
                        res.w = acc[ri][i][ci][3] * s - ma * mb[ci][3] + da * db[ci][3];
                        __builtin_nontemporal_store(res,
                            reinterpret_cast<nf4*>(&out_cov[rowo + ci * 64 + tx4]));
                    }
                }
            // mu-barrier above + next class's K-loop barriers provide all needed
            // fencing: mu/d arrays are only rewritten after next class's full
            // K-loop (many barriers away).
        } else {
            // w == 0: new_cov = cov_in * (1-w)
            for (int t = tid; t < TM * TM / 4; t += 256) {
                const int r = t >> 5;
                const int c4 = (t & 31) * 4;
                const size_t o = cbase + (size_t)(a0 + r) * A + b0 + c4;
                float4 co = *reinterpret_cast<const float4*>(&cov_in[o]);
                nf4 res;
                res.x = co.x * omw; res.y = co.y * omw; res.z = co.z * omw; res.w = co.w * omw;
                __builtin_nontemporal_store(res, reinterpret_cast<nf4*>(&out_cov[o]));
            }
        }
    }
}

extern "C" void kernel_launch(void* const* d_in, const int* in_sizes, int n_in,
                              void* d_out, int out_size, void* d_ws, size_t ws_size,
                              hipStream_t stream) {
    const float* feats  = (const float*)d_in[0];
    const float* y_s    = (const float*)d_in[1];
    const float* cov_in = (const float*)d_in[2];
    const float* Ave_in = (const float*)d_in[3];
    const float* Amount = (const float*)d_in[4];
    const int*   labels = (const int*)d_in[5];

    const int C = in_sizes[4];
    const int N = in_sizes[5];
    const int A = in_sizes[3] / C;

    float* out      = (float*)d_out;
    float* out_loss = out;
    float* out_cov  = out + 1;
    float* out_ave  = out_cov + (size_t)C * A * A;
    float* out_amt  = out_ave + (size_t)C * A;

    char* w8 = (char*)d_ws;
    int* offsets    = (int*)w8;   w8 += (size_t)(C + 1) * sizeof(int);
    int* idx_sorted = (int*)w8;   w8 += (size_t)N * sizeof(int);
    float* w_arr    = (float*)w8; w8 += (size_t)C * sizeof(float);
    float* inv_cs   = (float*)w8; w8 += (size_t)C * sizeof(float);

    prep_kernel<<<1, 1024, 0, stream>>>(labels, Amount, offsets, idx_sorted,
                                        w_arr, inv_cs, out_amt, out_loss, N, C);

    const int nxy = (A / TM) * (A / TM);              // 16 tile positions
    const int AZ = (C + nxy - 1) / nxy;               // ave-rider z-slices
    int CZ = 768 / nxy - LZ - AZ;                     // cov z-slices: ~3 blocks/CU total
    if (CZ < 1) CZ = 1;
    if (CZ > C) CZ = C;
    dim3 grid(A / TM, A / TM, LZ + AZ + CZ);          // riders at low z: dispatch first
    cov_kernel<<<grid, 256, 0, stream>>>(feats, cov_in, Ave_in, y_s, labels,
                                         idx_sorted, offsets, w_arr, inv_cs,
                                         out_cov, out_ave, out_loss, N, C, A,
                                         1.f / (float)N, AZ);
}

// Round 6
// 218.126 us; speedup vs baseline: 1.1523x; 1.1523x over previous
//
#include <hip/hip_runtime.h>

// N=4096, A=512, C=100 (derived at launch).
// Outputs flat: [loss(1), new_cov(C*A*A), new_ave(C*A), new_amount(C)]
//
// ONE dispatch (prep folded away: each block rebuilds its class's member list
// by scanning the 16KB labels array — L2-resident, removes the serial 1-block
// prep kernel + inter-dispatch gap). Grid (A/TM, A/TM, LZ+AZ+C):
//   z in [0,LZ)      : CE-loss rider blocks (need no per-class prep).
//   z in [LZ,LZ+AZ)  : new_ave rider blocks (one class per block; scan + colsum;
//                      also writes new_amount[c]).
//   z >= LZ+AZ       : 128x128 cov tile, class c = z-LZ-AZ (full 1600 blocks —
//                      round-5 persistence proved per-tile wall time is
//                      unchanged by persistence; keep max parallel slots).
// Cov tile: RAW outer products (E[xx^T]-mu mu^T identity), REGISTER-staged
// float4 gather (round-2 DMA staging amplified HBM 4x — keep feats L2-resident),
// LDS double-buffer -> ONE barrier per k-chunk, PACKED v_pk_fma_f32 inner loop
// (float2 acc: halves VALU issue slots vs 64x v_fmac, same FLOPs/VGPRs),
// per-thread scalar column sums, nontemporal streaming stores,
// cov_in read skipped when w==1 (always true for Amount=0 inputs).
//
// NOTE: plain __launch_bounds__(256). Round-3's (256,4) capped VGPR at 64 and
// spilled the 64-float accumulator to scratch (+395 MB HBM traffic, 2x dur).
// This kernel wants ~140-155 VGPRs / 3 waves per EU.
// out_loss zero-init via hipMemsetAsync (stream-ordered, graph-capturable).

#define TM 128
#define KC 16      // members per k-chunk
#define LSTR 132   // padded LDS row stride (floats)
#define LZ 8       // loss z-slices

typedef float nf4 __attribute__((ext_vector_type(4)));   // nontemporal vector
typedef float f2  __attribute__((ext_vector_type(2)));   // packed-FMA pair

// ---------------- mega: loss riders + ave riders + cov ----------------
__global__ __launch_bounds__(256) void mega_kernel(
    const float* __restrict__ feats, const float* __restrict__ cov_in,
    const float* __restrict__ Ave_in, const float* __restrict__ y_s,
    const int* __restrict__ labels, const float* __restrict__ Amount,
    float* __restrict__ out_cov, float* __restrict__ out_ave,
    float* __restrict__ out_amt, float* __restrict__ out_loss0,
    int N, int C, int A, float invN, int AZ) {

    const int nxy = gridDim.x * gridDim.y;
    const int bxy = blockIdx.y * gridDim.x + blockIdx.x;
    const int tid = threadIdx.x;

    // ---- loss rider blocks (z in [0, LZ)): LZ*nxy blocks, 4 waves each ----
    if ((int)blockIdx.z < LZ) {
        __shared__ float bsum[4];
        const int lane = tid & 63;
        const int wv = tid >> 6;
        const int bid = (int)blockIdx.z * nxy + bxy;
        const int nwaves = LZ * nxy * 4;
        const int gw = bid * 4 + wv;
        float wsum = 0.f;
        for (int r = gw; r < N; r += nwaves) {
            const float* row = y_s + (size_t)r * C;
            float m = -1e30f;
            for (int col = lane; col < C; col += 64) m = fmaxf(m, row[col]);
            #pragma unroll
            for (int off = 32; off > 0; off >>= 1) m = fmaxf(m, __shfl_xor(m, off));
            float se = 0.f;
            for (int col = lane; col < C; col += 64) se += __expf(row[col] - m);
            #pragma unroll
            for (int off = 32; off > 0; off >>= 1) se += __shfl_xor(se, off);
            if (lane == 0) wsum += -(row[labels[r]] - m - __logf(se));
        }
        if (lane == 0) bsum[wv] = wsum;
        __syncthreads();
        if (tid == 0)
            atomicAdd(out_loss0, (bsum[0] + bsum[1] + bsum[2] + bsum[3]) * invN);
        return;
    }

    // ---- ave rider blocks (z in [LZ, LZ+AZ)): one class per block ----
    if ((int)blockIdx.z < LZ + AZ) {
        __shared__ int idxs[256];
        __shared__ int acnt;
        const int bid = ((int)blockIdx.z - LZ) * nxy + bxy;
        if (bid >= C) return;
        const int c = bid;
        if (tid == 0) acnt = 0;
        __syncthreads();
        for (int i = tid; i < N; i += 256)
            if (labels[i] == c) { int p = atomicAdd(&acnt, 1); if (p < 256) idxs[p] = i; }
        __syncthreads();
        const int nc = min(acnt, 256);
        const float cf = (float)nc;
        const float ic = 1.f / fmaxf(cf, 1.f);
        const float am = Amount[c];
        const float dn = cf + am;
        const float w = dn > 0.f ? cf / dn : 0.f;
        if (tid == 0) out_amt[c] = am + cf;
        for (int c0 = 0; c0 < A; c0 += 512) {
            const int colA = c0 + tid;
            const int colB = c0 + 256 + tid;
            float s0 = 0.f, s1 = 0.f;
            int j = 0;
            for (; j + 3 < nc; j += 4) {
                const float* f0 = feats + (size_t)idxs[j] * A;
                const float* f1 = feats + (size_t)idxs[j + 1] * A;
                const float* f2p = feats + (size_t)idxs[j + 2] * A;
                const float* f3 = feats + (size_t)idxs[j + 3] * A;
                if (colA < A) s0 += f0[colA] + f1[colA] + f2p[colA] + f3[colA];
                if (colB < A) s1 += f0[colB] + f1[colB] + f2p[colB] + f3[colB];
            }
            for (; j < nc; ++j) {
                const float* fr = feats + (size_t)idxs[j] * A;
                if (colA < A) s0 += fr[colA];
                if (colB < A) s1 += fr[colB];
            }
            if (colA < A)
                out_ave[(size_t)c * A + colA] =
                    Ave_in[(size_t)c * A + colA] * (1.f - w) + (s0 * ic) * w;
            if (colB < A)
                out_ave[(size_t)c * A + colB] =
                    Ave_in[(size_t)c * A + colB] * (1.f - w) + (s1 * ic) * w;
        }
        return;
    }

    // ---- cov tile: class c, fixed 128x128 output position ----
    const int c  = (int)blockIdx.z - LZ - AZ;
    const int a0 = blockIdx.y * TM;
    const int b0 = blockIdx.x * TM;

    // [buf][0=A-tile,1=B-tile][k][col], padded stride
    __shared__ float Xs[2][2][KC][LSTR];
    __shared__ float muA[TM], muB[TM], dA[TM], dB[TM];
    __shared__ int idxbuf[256];
    __shared__ int ccnt;

    const int ty = tid >> 4, tx = tid & 15;
    const int ty4 = ty * 4, tx4 = tx * 4;

    // scan labels -> member list for class c (L2-resident 16KB, 16 loads/thread)
    if (tid == 0) ccnt = 0;
    __syncthreads();
    for (int i = tid; i < N; i += 256)
        if (labels[i] == c) { int p = atomicAdd(&ccnt, 1); if (p < 256) idxbuf[p] = i; }
    __syncthreads();
    const int nc = min(ccnt, 256);

    const float cf  = (float)nc;
    const float ic  = 1.f / fmaxf(cf, 1.f);
    const float am  = Amount[c];
    const float dn  = cf + am;
    const float w   = dn > 0.f ? cf / dn : 0.f;
    const float omw = 1.f - w;
    const float s   = ic * w;
    const float aw  = w * omw;
    const size_t cbase = (size_t)c * A * A;

    if (s > 0.f) {
        const int nchunks = (nc + KC - 1) / KC;
        const int li = ty;            // staging member row (0..15)
        const int cg = tx4;           // staging col group

        float4 v0, v1, v2, v3;        // pipeline registers (RAW values)
        auto LOADV = [&](int ch) {
            const int slot = ch * KC + li;
            v0 = make_float4(0.f, 0.f, 0.f, 0.f); v1 = v0; v2 = v0; v3 = v0;
            if (slot < nc) {
                int row = idxbuf[slot];
                const float* fr = feats + (size_t)row * A;
                v0 = *reinterpret_cast<const float4*>(fr + a0 + cg);
                v1 = *reinterpret_cast<const float4*>(fr + a0 + cg + 64);
                v2 = *reinterpret_cast<const float4*>(fr + b0 + cg);
                v3 = *reinterpret_cast<const float4*>(fr + b0 + cg + 64);
            }
        };
        auto STORE_LDS = [&](int b) {
            *reinterpret_cast<float4*>(&Xs[b][0][li][cg])      = v0;
            *reinterpret_cast<float4*>(&Xs[b][0][li][cg + 64]) = v1;
            *reinterpret_cast<float4*>(&Xs[b][1][li][cg])      = v2;
            *reinterpret_cast<float4*>(&Xs[b][1][li][cg + 64]) = v3;
        };

        // packed-fp32 accumulator: acc[ri][i][ci][jj] = cols {jj*2, jj*2+1}
        f2 acc[2][4][2][2] = {};
        if (omw != 0.f) {
            // fold cov_in*(1-w) into acc init; skipped when w==1
            const float sc = omw / s;
            #pragma unroll
            for (int ri = 0; ri < 2; ++ri)
                #pragma unroll
                for (int i = 0; i < 4; ++i) {
                    const size_t rowo = cbase + (size_t)(a0 + ri * 64 + ty4 + i) * A + b0;
                    #pragma unroll
                    for (int ci = 0; ci < 2; ++ci) {
                        float4 co = *reinterpret_cast<const float4*>(&cov_in[rowo + ci * 64 + tx4]);
                        f2 t0; t0.x = co.x * sc; t0.y = co.y * sc;
                        f2 t1; t1.x = co.z * sc; t1.y = co.w * sc;
                        acc[ri][i][ci][0] = t0;
                        acc[ri][i][ci][1] = t1;
                    }
                }
        }

        float csum = 0.f;             // this thread's column sum
        const int cside = tid >> 7;   // 0: A-tile, 1: B-tile
        const int ccol  = tid & 127;

        // prologue: chunk 0 -> regs -> buf0 (idxbuf visible after scan barrier)
        LOADV(0);
        STORE_LDS(0);

        for (int ch = 0; ch < nchunks; ++ch) {
            const int cur = ch & 1;
            __syncthreads();          // buf[cur] visible; prev reads of buf[cur^1] done
            if (ch + 1 < nchunks) LOADV(ch + 1);   // loads fly under the FMA burst

            const int kn = min(KC, nc - ch * KC);
            if (kn == KC) {
                #pragma unroll
                for (int k = 0; k < KC; ++k) {
                    float4 a0v = *reinterpret_cast<const float4*>(&Xs[cur][0][k][ty4]);
                    float4 a1v = *reinterpret_cast<const float4*>(&Xs[cur][0][k][64 + ty4]);
                    float4 b0v = *reinterpret_cast<const float4*>(&Xs[cur][1][k][tx4]);
                    float4 b1v = *reinterpret_cast<const float4*>(&Xs[cur][1][k][64 + tx4]);
                    float af[2][4] = {{a0v.x, a0v.y, a0v.z, a0v.w}, {a1v.x, a1v.y, a1v.z, a1v.w}};
                    f2 bf[2][2];
                    bf[0][0].x = b0v.x; bf[0][0].y = b0v.y;
                    bf[0][1].x = b0v.z; bf[0][1].y = b0v.w;
                    bf[1][0].x = b1v.x; bf[1][0].y = b1v.y;
                    bf[1][1].x = b1v.z; bf[1][1].y = b1v.w;
                    #pragma unroll
                    for (int ri = 0; ri < 2; ++ri)
                        #pragma unroll
                        for (int i = 0; i < 4; ++i) {
                            f2 av; av.x = af[ri][i]; av.y = af[ri][i];
                            #pragma unroll
                            for (int ci = 0; ci < 2; ++ci) {
                                acc[ri][i][ci][0] = __builtin_elementwise_fma(av, bf[ci][0], acc[ri][i][ci][0]);
                                acc[ri][i][ci][1] = __builtin_elementwise_fma(av, bf[ci][1], acc[ri][i][ci][1]);
                            }
                        }
                }
            } else {
                for (int k = 0; k < kn; ++k) {
                    float4 a0v = *reinterpret_cast<const float4*>(&Xs[cur][0][k][ty4]);
                    float4 a1v = *reinterpret_cast<const float4*>(&Xs[cur][0][k][64 + ty4]);
                    float4 b0v = *reinterpret_cast<const float4*>(&Xs[cur][1][k][tx4]);
                    float4 b1v = *reinterpret_cast<const float4*>(&Xs[cur][1][k][64 + tx4]);
                    float af[2][4] = {{a0v.x, a0v.y, a0v.z, a0v.w}, {a1v.x, a1v.y, a1v.z, a1v.w}};
                    f2 bf[2][2];
                    bf[0][0].x = b0v.x; bf[0][0].y = b0v.y;
                    bf[0][1].x = b0v.z; bf[0][1].y = b0v.w;
                    bf[1][0].x = b1v.x; bf[1][0].y = b1v.y;
                    bf[1][1].x = b1v.z; bf[1][1].y = b1v.w;
                    #pragma unroll
                    for (int ri = 0; ri < 2; ++ri)
                        #pragma unroll
                        for (int i = 0; i < 4; ++i) {
                            f2 av; av.x = af[ri][i]; av.y = af[ri][i];
                            #pragma unroll
                            for (int ci = 0; ci < 2; ++ci) {
                                acc[ri][i][ci][0] = __builtin_elementwise_fma(av, bf[ci][0], acc[ri][i][ci][0]);
                                acc[ri][i][ci][1] = __builtin_elementwise_fma(av, bf[ci][1], acc[ri][i][ci][1]);
                            }
                        }
                }
            }

            // column-sum pass on current buffer (zero-filled tail rows contribute 0)
            for (int k = 0; k < kn; ++k) csum += Xs[cur][cside][k][ccol];

            if (ch + 1 < nchunks) STORE_LDS(cur ^ 1);    // waits vmcnt on LOADV regs
        }

        // mu / d arrays from per-thread column sums (tid<128: A-side, else B-side)
        {
            float mu = csum * ic;
            if (tid < 128) {
                muA[ccol] = mu;
                dA[ccol] = Ave_in[(size_t)c * A + a0 + ccol] - mu;
            } else {
                muB[ccol] = mu;
                dB[ccol] = Ave_in[(size_t)c * A + b0 + ccol] - mu;
            }
        }
        __syncthreads();

        // epilogue: out = acc*s - w*muA*muB + w(1-w)*dA*dB ; nontemporal stream
        float mb[2][4], db[2][4];
        #pragma unroll
        for (int ci = 0; ci < 2; ++ci)
            #pragma unroll
            for (int j = 0; j < 4; ++j) {
                mb[ci][j] = muB[ci * 64 + tx4 + j];
                db[ci][j] = dB[ci * 64 + tx4 + j];
            }

        #pragma unroll
        for (int ri = 0; ri < 2; ++ri)
            #pragma unroll
            for (int i = 0; i < 4; ++i) {
                float ma = w  * muA[ri * 64 + ty4 + i];
                float da = aw * dA[ri * 64 + ty4 + i];
                const size_t rowo = cbase + (size_t)(a0 + ri * 64 + ty4 + i) * A + b0;
                #pragma unroll
                for (int ci = 0; ci < 2; ++ci) {
                    nf4 res;
                    res.x = acc[ri][i][ci][0].x * s - ma * mb[ci][0] + da * db[ci][0];
                    res.y = acc[ri][i][ci][0].y * s - ma * mb[ci][1] + da * db[ci][1];
                    res.z = acc[ri][i][ci][1].x * s - ma * mb[ci][2] + da * db[ci][2];
                    res.w = acc[ri][i][ci][1].y * s - ma * mb[ci][3] + da * db[ci][3];
                    __builtin_nontemporal_store(res,
                        reinterpret_cast<nf4*>(&out_cov[rowo + ci * 64 + tx4]));
                }
            }
    } else {
        // w == 0: new_cov = cov_in * (1-w)
        for (int t = tid; t < TM * TM / 4; t += 256) {
            const int r = t >> 5;
            const int c4 = (t & 31) * 4;
            const size_t o = cbase + (size_t)(a0 + r) * A + b0 + c4;
            float4 co = *reinterpret_cast<const float4*>(&cov_in[o]);
            nf4 res;
            res.x = co.x * omw; res.y = co.y * omw; res.z = co.z * omw; res.w = co.w * omw;
            __builtin_nontemporal_store(res, reinterpret_cast<nf4*>(&out_cov[o]));
        }
    }
}

extern "C" void kernel_launch(void* const* d_in, const int* in_sizes, int n_in,
                              void* d_out, int out_size, void* d_ws, size_t ws_size,
                              hipStream_t stream) {
    const float* feats  = (const float*)d_in[0];
    const float* y_s    = (const float*)d_in[1];
    const float* cov_in = (const float*)d_in[2];
    const float* Ave_in = (const float*)d_in[3];
    const float* Amount = (const float*)d_in[4];
    const int*   labels = (const int*)d_in[5];

    const int C = in_sizes[4];
    const int N = in_sizes[5];
    const int A = in_sizes[3] / C;

    float* out      = (float*)d_out;
    float* out_loss = out;
    float* out_cov  = out + 1;
    float* out_ave  = out_cov + (size_t)C * A * A;
    float* out_amt  = out_ave + (size_t)C * A;

    hipMemsetAsync(out_loss, 0, sizeof(float), stream);   // loss accumulator init

    const int nxy = (A / TM) * (A / TM);
    const int AZ = (C + nxy - 1) / nxy;       // ave-rider z-slices
    dim3 grid(A / TM, A / TM, LZ + AZ + C);   // riders at low z: dispatch first
    mega_kernel<<<grid, 256, 0, stream>>>(feats, cov_in, Ave_in, y_s, labels, Amount,
                                          out_cov, out_ave, out_amt, out_loss,
                                          N, C, A, 1.f / (float)N, AZ);
}